// Round 5
// baseline (246.562 us; speedup 1.0000x reference)
//
#include <hip/hip_runtime.h>
#include <math.h>

#define NHID 128

typedef __bf16 bf16x8 __attribute__((ext_vector_type(8)));
typedef float f32x4 __attribute__((ext_vector_type(4)));

__device__ __forceinline__ unsigned int pack_bf16_rn(float f0, float f1) {
  unsigned int u0 = __float_as_uint(f0) + 0x8000u;
  unsigned int u1 = __float_as_uint(f1) + 0x8000u;
  return __builtin_amdgcn_perm(u1, u0, 0x07060302u);   // mem order: lo=f0, hi=f1
}
__device__ __forceinline__ unsigned short f2bf(float f) {
  return (unsigned short)((__float_as_uint(f) + 0x8000u) >> 16);
}
union frag_u { unsigned int u[4]; bf16x8 v; };

// ============================================================================
// Phase 1: per-node C rows (512 B): u = x@W1a + b1 (bf16), v = x@W1b (bf16),
// both stored in MFMA-D-natural permuted order: u[i=m15*8+c] = col n=c*16+m15.
// Dense GEMM M=n_nodes, N=256, K=128; M=32 per wave; dense 16B stores.
// ============================================================================
__global__ __launch_bounds__(256, 2)   // 256-reg cap (proven no-spill regime)
void precompute_uv(const float* __restrict__ inputs,
                   const float* __restrict__ W1,
                   const float* __restrict__ bias1,
                   unsigned short* __restrict__ C,
                   int n_nodes)
{
  // Combined B (K=128, N=256): Bc[k][n] = n<128 ? W1[k][n] : W1[128+k][n-128]
  // in MFMA B-frag-major order (verified r1-r4): 64 KB -> 2 blocks/CU.
  __shared__ __align__(16) unsigned short sB[4 * 16 * 64 * 8];

  const int tid = threadIdx.x;
  for (int i = tid; i < 256 * NHID / 4; i += 256) {
    float4 w = ((const float4*)W1)[i];
    int base = i * 4;
    int r  = base >> 7;          // W1 row (0..255)
    int n0 = base & 127;
    int k  = (r < 128) ? r : (r - 128);
    int nb = (r < 128) ? n0 : (n0 + 128);
    int ks = k >> 5, qq = (k >> 3) & 3, j = k & 7;
    #pragma unroll
    for (int c = 0; c < 4; ++c) {
      int n = nb + c;
      sB[(((ks * 16 + (n >> 4)) * 64) + (qq * 16 + (n & 15))) * 8 + j] = f2bf((&w.x)[c]);
    }
  }
  __syncthreads();   // only barrier

  const int lane = tid & 63;
  const int wv   = tid >> 6;
  const int m15  = lane & 15;
  const int q    = lane >> 4;

  float b1v[8];
  #pragma unroll
  for (int nt = 0; nt < 8; ++nt) b1v[nt] = bias1[nt * 16 + m15];

  const bf16x8* __restrict__ bfrags = (const bf16x8*)sB;
  const int gwave   = blockIdx.x * 4 + wv;
  const int nwaves  = gridDim.x * 4;
  const int nstrips = (n_nodes + 31) >> 5;   // 32-row strips

  for (int strip = gwave; strip < nstrips; strip += nwaves) {
    const int base = strip * 32;

    const float* ap[2];
    #pragma unroll
    for (int s = 0; s < 2; ++s) {
      int row = base + s * 16 + m15;
      if (row >= n_nodes) row = n_nodes - 1;
      ap[s] = inputs + (size_t)row * NHID;
    }

    f32x4 acc[2][16];
    #pragma unroll
    for (int s = 0; s < 2; ++s)
      #pragma unroll
      for (int nt = 0; nt < 16; ++nt) acc[s][nt] = (f32x4){0.f, 0.f, 0.f, 0.f};

    // depth-2 ring over ks of raw fp32 A (A-frag: row=m15, k=ks*32+q*8+j)
    float4 r0[2][2], r1[2][2];
    #pragma unroll
    for (int s = 0; s < 2; ++s) {
      r0[0][s] = *(const float4*)(ap[s] + q * 8);
      r1[0][s] = *(const float4*)(ap[s] + q * 8 + 4);
    }

    #pragma unroll
    for (int ks = 0; ks < 4; ++ks) {
      const int cur = ks & 1;
      if (ks < 3) {
        #pragma unroll
        for (int s = 0; s < 2; ++s) {
          r0[cur ^ 1][s] = *(const float4*)(ap[s] + (ks + 1) * 32 + q * 8);
          r1[cur ^ 1][s] = *(const float4*)(ap[s] + (ks + 1) * 32 + q * 8 + 4);
        }
      }
      bf16x8 af[2];
      #pragma unroll
      for (int s = 0; s < 2; ++s) {
        frag_u cv;
        cv.u[0] = pack_bf16_rn(r0[cur][s].x, r0[cur][s].y);
        cv.u[1] = pack_bf16_rn(r0[cur][s].z, r0[cur][s].w);
        cv.u[2] = pack_bf16_rn(r1[cur][s].x, r1[cur][s].y);
        cv.u[3] = pack_bf16_rn(r1[cur][s].z, r1[cur][s].w);
        af[s] = cv.v;
      }
      const bf16x8* bp = bfrags + (ks * 16) * 64 + lane;
      #pragma unroll
      for (int nt = 0; nt < 16; ++nt) {
        bf16x8 bf = bp[nt * 64];
        acc[0][nt] = __builtin_amdgcn_mfma_f32_16x16x32_bf16(af[0], bf, acc[0][nt], 0, 0, 0);
        acc[1][nt] = __builtin_amdgcn_mfma_f32_16x16x32_bf16(af[1], bf, acc[1][nt], 0, 0, 0);
      }
    }

    // Epilogue: D col = lane&15, row = q*4+r. Lane packs its 8 u vals (+b1)
    // and 8 v vals into one 16B chunk each -> dense 256B row-halves per instr.
    #pragma unroll
    for (int s = 0; s < 2; ++s) {
      #pragma unroll
      for (int r = 0; r < 4; ++r) {
        int m = base + s * 16 + q * 4 + r;
        if (m < n_nodes) {
          uint4 up, vp;
          up.x = pack_bf16_rn(acc[s][0][r] + b1v[0], acc[s][1][r] + b1v[1]);
          up.y = pack_bf16_rn(acc[s][2][r] + b1v[2], acc[s][3][r] + b1v[3]);
          up.z = pack_bf16_rn(acc[s][4][r] + b1v[4], acc[s][5][r] + b1v[5]);
          up.w = pack_bf16_rn(acc[s][6][r] + b1v[6], acc[s][7][r] + b1v[7]);
          vp.x = pack_bf16_rn(acc[s][8][r],  acc[s][9][r]);
          vp.y = pack_bf16_rn(acc[s][10][r], acc[s][11][r]);
          vp.z = pack_bf16_rn(acc[s][12][r], acc[s][13][r]);
          vp.w = pack_bf16_rn(acc[s][14][r], acc[s][15][r]);
          unsigned short* crow = C + (size_t)m * 256;
          *(uint4*)(crow + m15 * 8)       = up;   // u-half: bytes m15*16..+16
          *(uint4*)(crow + 128 + m15 * 8) = vp;   // v-half
        }
      }
    }
  }
}

// ============================================================================
// Phase 2: out[e] = sigmoid( sum_i relu(u[x[e]][i] + v[y[e]][i]) * W2[j(i)] + b2 )
// 16 lanes/edge, 4 edges/wave/iter, depth-2 row-gather pipeline.
// Permutation: chunk elem c of lane sub -> j = c*16 + sub.
// ============================================================================
__global__ __launch_bounds__(256, 4)
void edge_decode(const unsigned short* __restrict__ C,
                 const int* __restrict__ x_idx,
                 const int* __restrict__ y_idx,
                 const float* __restrict__ W2,
                 const float* __restrict__ bias2,
                 float* __restrict__ out,
                 int n_edges)
{
  const int tid  = threadIdx.x;
  const int lane = tid & 63;
  const int wv   = tid >> 6;
  const int sub  = lane & 15;   // 16-B slice within the 256-B half-row
  const int eo   = lane >> 4;   // edge within the wave's 4-edge batch

  float w2v[8];
  #pragma unroll
  for (int c = 0; c < 8; ++c) w2v[c] = W2[c * 16 + sub];
  const float b2 = bias2[0];

  const int gwave = blockIdx.x * 4 + wv;
  const int SE    = gridDim.x * 4 * 4;
  int e = gwave * 4;
  if (e >= n_edges) return;

  auto clampe = [n_edges](int x) { return (x < n_edges) ? x : (n_edges - 1); };

  // idx pairs for iters 0,1,2; row slots for iters 0,1
  int xi[2], yi[2], xiN, yiN;
  {
    int e0 = clampe(e + eo), e1 = clampe(e + SE + eo), e2 = clampe(e + 2 * SE + eo);
    xi[0] = x_idx[e0]; yi[0] = y_idx[e0];
    xi[1] = x_idx[e1]; yi[1] = y_idx[e1];
    xiN = x_idx[e2];   yiN = y_idx[e2];
  }
  uint4 Ru[2], Rv[2];
  #pragma unroll
  for (int s = 0; s < 2; ++s) {
    Ru[s] = *(const uint4*)(C + (size_t)xi[s] * 256 + sub * 8);
    Rv[s] = *(const uint4*)(C + (size_t)yi[s] * 256 + 128 + sub * 8);
  }

  int it = 0;
  #pragma unroll 2
  for (; e < n_edges; e += SE, ++it) {
    const int s = it & 1;

    float t = 0.f;
    #pragma unroll
    for (int p = 0; p < 4; ++p) {
      unsigned int a = (&Ru[s].x)[p], b = (&Rv[s].x)[p];
      float h0 = fmaxf(__uint_as_float(a << 16)          + __uint_as_float(b << 16),          0.f);
      float h1 = fmaxf(__uint_as_float(a & 0xffff0000u) + __uint_as_float(b & 0xffff0000u), 0.f);
      t = fmaf(h0, w2v[2 * p], t);
      t = fmaf(h1, w2v[2 * p + 1], t);
    }
    t += __shfl_xor(t, 1);
    t += __shfl_xor(t, 2);
    t += __shfl_xor(t, 4);
    t += __shfl_xor(t, 8);
    int epos = e + eo;
    if (sub == 0 && epos < n_edges)
      out[epos] = 1.f / (1.f + __expf(-(t + b2)));

    // refill slot s with rows for iter it+2; fetch idx for it+3
    Ru[s] = *(const uint4*)(C + (size_t)xiN * 256 + sub * 8);
    Rv[s] = *(const uint4*)(C + (size_t)yiN * 256 + 128 + sub * 8);
    int e3 = clampe(e + 3 * SE + eo);
    xiN = x_idx[e3]; yiN = y_idx[e3];
  }
}

// ============================================================================
// Fallback (ws too small): round-3/4 fused kernel (proven correct).
// ============================================================================
__global__ __launch_bounds__(256, 2)
void mlp_edge_fused(const float* __restrict__ inputs,
                    const int* __restrict__ x_idx,
                    const int* __restrict__ y_idx,
                    const float* __restrict__ W1,
                    const float* __restrict__ bias1,
                    const float* __restrict__ W2,
                    const float* __restrict__ bias2,
                    float* __restrict__ out,
                    int n_edges)
{
  __shared__ __align__(16) unsigned short sB[8 * 8 * 64 * 8];
  const int tid = threadIdx.x;
  for (int i = tid; i < 256 * NHID / 4; i += 256) {
    float4 w = ((const float4*)W1)[i];
    int base = i * 4;
    int k  = base >> 7;
    int n0 = base & 127;
    int ks = k >> 5, qq = (k >> 3) & 3, j = k & 7;
    #pragma unroll
    for (int c = 0; c < 4; ++c) {
      int n = n0 + c;
      sB[(((ks * 8 + (n >> 4)) * 64) + (qq * 16 + (n & 15))) * 8 + j] = f2bf((&w.x)[c]);
    }
  }
  __syncthreads();

  const int lane = tid & 63;
  const int wv   = tid >> 6;
  const int m15  = lane & 15;
  const int q    = lane >> 4;

  float b1v[8], w2v[8];
  #pragma unroll
  for (int nt = 0; nt < 8; ++nt) {
    b1v[nt] = bias1[nt * 16 + m15];
    w2v[nt] = W2[nt * 16 + m15];
  }
  const float b2 = bias2[0];

  const int gwave   = blockIdx.x * 4 + wv;
  const int nwaves  = gridDim.x * 4;
  const int nstrips = (n_edges + 15) >> 4;
  const bf16x8* __restrict__ bfrags = (const bf16x8*)sB;

  int ix_n = 0, iy_n = 0;
  if (gwave < nstrips) {
    int e = gwave * 16 + m15; if (e >= n_edges) e = n_edges - 1;
    ix_n = x_idx[e]; iy_n = y_idx[e];
  }

  for (int strip = gwave; strip < nstrips; strip += nwaves) {
    const float* ax = inputs + (size_t)ix_n * NHID;
    const float* ay = inputs + (size_t)iy_n * NHID;
    int nxt = strip + nwaves;
    if (nxt < nstrips) {
      int e = nxt * 16 + m15; if (e >= n_edges) e = n_edges - 1;
      ix_n = x_idx[e]; iy_n = y_idx[e];
    }
    float4 ring0[4], ring1[4];
    #pragma unroll
    for (int d = 0; d < 4; ++d) {
      ring0[d] = *(const float4*)(ax + d * 32 + q * 8);
      ring1[d] = *(const float4*)(ax + d * 32 + q * 8 + 4);
    }
    f32x4 acc[8];
    #pragma unroll
    for (int nt = 0; nt < 8; ++nt) acc[nt] = (f32x4){0.f, 0.f, 0.f, 0.f};
    #pragma unroll
    for (int ks = 0; ks < 8; ++ks) {
      float4 a0 = ring0[ks & 3], a1 = ring1[ks & 3];
      frag_u cv;
      cv.u[0] = pack_bf16_rn(a0.x, a0.y);
      cv.u[1] = pack_bf16_rn(a0.z, a0.w);
      cv.u[2] = pack_bf16_rn(a1.x, a1.y);
      cv.u[3] = pack_bf16_rn(a1.z, a1.w);
      bf16x8 af = cv.v;
      if (ks < 4) {
        ring0[ks & 3] = *(const float4*)(ay + ks * 32 + q * 8);
        ring1[ks & 3] = *(const float4*)(ay + ks * 32 + q * 8 + 4);
      }
      const bf16x8* bp = bfrags + (ks * 8) * 64 + lane;
      #pragma unroll
      for (int nt = 0; nt < 8; ++nt)
        acc[nt] = __builtin_amdgcn_mfma_f32_16x16x32_bf16(af, bp[nt * 64], acc[nt], 0, 0, 0);
    }
    float4 sv;
    #pragma unroll
    for (int r = 0; r < 4; ++r) {
      float t = 0.f;
      #pragma unroll
      for (int nt = 0; nt < 8; ++nt) {
        float h = acc[nt][r] + b1v[nt];
        h = fmaxf(h, 0.f);
        t = fmaf(h, w2v[nt], t);
      }
      t += __shfl_xor(t, 1);
      t += __shfl_xor(t, 2);
      t += __shfl_xor(t, 4);
      t += __shfl_xor(t, 8);
      (&sv.x)[r] = t;
    }
    if (m15 == 0) {
      int e = strip * 16 + q * 4;
      float4 ov;
      #pragma unroll
      for (int r = 0; r < 4; ++r)
        (&ov.x)[r] = 1.f / (1.f + __expf(-((&sv.x)[r] + b2)));
      if (e + 3 < n_edges) *(float4*)(out + e) = ov;
      else {
        #pragma unroll
        for (int r = 0; r < 4; ++r)
          if (e + r < n_edges) out[e + r] = (&ov.x)[r];
      }
    }
  }
}

extern "C" void kernel_launch(void* const* d_in, const int* in_sizes, int n_in,
                              void* d_out, int out_size, void* d_ws, size_t ws_size,
                              hipStream_t stream) {
  const float* inputs = (const float*)d_in[0];
  const int*   x_idx  = (const int*)d_in[1];
  const int*   y_idx  = (const int*)d_in[2];
  const float* W1     = (const float*)d_in[3];
  const float* bias1  = (const float*)d_in[4];
  const float* W2     = (const float*)d_in[5];
  const float* bias2  = (const float*)d_in[6];
  float* out = (float*)d_out;
  const int n_edges = in_sizes[1];
  const int n_nodes = in_sizes[0] / NHID;

  const size_t need = (size_t)n_nodes * 256 * sizeof(unsigned short);
  if (ws_size >= need) {
    unsigned short* C = (unsigned short*)d_ws;
    hipLaunchKernelGGL(precompute_uv, dim3(512), dim3(256), 0, stream,
                       inputs, W1, bias1, C, n_nodes);
    hipLaunchKernelGGL(edge_decode, dim3(1024), dim3(256), 0, stream,
                       C, x_idx, y_idx, W2, bias2, out, n_edges);
  } else {
    hipLaunchKernelGGL(mlp_edge_fused, dim3(512), dim3(256), 0, stream,
                       inputs, x_idx, y_idx, W1, bias1, W2, bias2, out, n_edges);
  }
}